// Round 3
// baseline (136.045 us; speedup 1.0000x reference)
//
#include <hip/hip_runtime.h>
#include <math.h>

#define NH   32
#define NKVH 8
#define HD   64
#define WIN  256
#define BB   2
#define SS   2048

typedef short short8 __attribute__((ext_vector_type(8)));
typedef float f32x4  __attribute__((ext_vector_type(4)));

__device__ __forceinline__ ushort f2bf(float x) {
    union { float f; unsigned u; } v; v.f = x;
    unsigned u = v.u + 0x7FFF + ((v.u >> 16) & 1);   // RNE
    return (ushort)(u >> 16);
}

__device__ __forceinline__ int cvtpk_bf16(float lo, float hi) {
    int r;
    asm("v_cvt_pk_bf16_f32 %0, %1, %2" : "=v"(r) : "v"(lo), "v"(hi));
    return r;
}

// ---- fused pre-pass: RoPE K -> bf16 [b][kvh][s][d]; V -> bf16 CHUNK-MAJOR ----
// Vt layout: [(b,kvh)][chunk=s/32][d][s%32] -- each 32-key chunk contiguous 4KB.
__global__ __launch_bounds__(256) void prep_kv(const float* __restrict__ K,
                                               const float* __restrict__ V,
                                               ushort* __restrict__ Kr,
                                               ushort* __restrict__ Vt) {
    __shared__ ushort tile[32][65];
    const int bidx = blockIdx.x;                // (b, kvh, sblk): 2*8*64
    const int sblk = bidx & 63;
    const int s0   = sblk * 32;
    const int kvh  = (bidx >> 6) & 7;
    const int b    = bidx >> 9;
    const int d = threadIdx.x & 63, g = threadIdx.x >> 6;   // g 0..3, 8 rows each

    const float inv = __powf(10000.f, -(float)(d & 31) * (1.f / 32.f));

    float kv[8], vv[8];
#pragma unroll
    for (int i = 0; i < 8; ++i) {
        int s = s0 + g * 8 + i;
        kv[i] = K[(size_t)(b * SS + s) * (NKVH * HD) + kvh * HD + d];
        vv[i] = V[(size_t)(b * SS + s) * (NKVH * HD) + kvh * HD + d];
    }
#pragma unroll
    for (int i = 0; i < 8; ++i) {
        int s  = s0 + g * 8 + i;
        int sl = g * 8 + i;
        float partner = __shfl(kv[i], d ^ 32, 64);
        float sn, cs;
        __sincosf((float)s * inv, &sn, &cs);
        float krot = kv[i] * cs + ((d < 32) ? -partner : partner) * sn;
        Kr[((size_t)(b * NKVH + kvh) * SS + s) * HD + d] = f2bf(krot);
        tile[sl][d] = f2bf(vv[i]);
    }
    __syncthreads();
    // transpose-store one contiguous 4KB chunk block [d=0..63][s%32], ushort2-vectorized
    ushort* vb = Vt + (size_t)(b * NKVH + kvh) * HD * SS + (size_t)sblk * (HD * 32);
    const int sl2 = (threadIdx.x & 15) * 2, drg = threadIdx.x >> 4;   // drg 0..15
#pragma unroll
    for (int i = 0; i < 4; ++i) {
        int dr = drg * 4 + i;
        ushort2 u = make_ushort2(tile[sl2][dr], tile[sl2 + 1][dr]);
        *(ushort2*)(vb + dr * 32 + sl2) = u;
    }
}

// ---- main: v4 key-split. Block = 128 thr = 2 waves = 1 head x 2 window-halves.
// exp (no running max) => partial acc/psum over disjoint key ranges are additive;
// wave 1 dumps partials to LDS, wave 0 combines + writes O.
__global__ __launch_bounds__(128) void attn_mfma(const float* __restrict__ Q,
                                                 const ushort* __restrict__ Kr,
                                                 const ushort* __restrict__ Vt,
                                                 float* __restrict__ O) {
    __shared__ float cbuf[32][65];
    __shared__ float csum[32];
    const int wv = threadIdx.x >> 6, lane = threadIdx.x & 63;
    const int lo16 = lane & 15, quad = lane >> 4;
    // bijective XCD swizzle: 4096 wg = 8 XCD * 512 contiguous
    const int bidx = (blockIdx.x & 7) * 512 + (blockIdx.x >> 3);
    const int h2   = bidx & 3;
    const int qblk = (bidx >> 2) & 63;
    const int kvh  = (bidx >> 8) & 7;
    const int b    = bidx >> 11;
    const int h    = kvh * 4 + h2;
    const int q0   = qblk * 32;

    float invf[8];
#pragma unroll
    for (int j = 0; j < 8; ++j)
        invf[j] = __powf(10000.f, -(float)(quad * 8 + j) * (1.f / 32.f));

    // Q load + RoPE + scale -> MFMA B-operand-shaped regs
    short8 aq[2][2];
#pragma unroll
    for (int t = 0; t < 2; ++t) {
        int qi = q0 + t * 16 + lo16;
        const float* qrow = Q + (size_t)(b * SS + qi) * (NH * HD) + h * HD;
        float lo[8], hi[8];
        *(float4*)(lo)     = *(const float4*)(qrow + quad * 8);
        *(float4*)(lo + 4) = *(const float4*)(qrow + quad * 8 + 4);
        *(float4*)(hi)     = *(const float4*)(qrow + 32 + quad * 8);
        *(float4*)(hi + 4) = *(const float4*)(qrow + 32 + quad * 8 + 4);
#pragma unroll
        for (int j = 0; j < 8; ++j) {
            float sn, cs;
            __sincosf((float)qi * invf[j], &sn, &cs);
            aq[t][0][j] = (short)f2bf((lo[j] * cs - hi[j] * sn) * 0.125f);
            aq[t][1][j] = (short)f2bf((hi[j] * cs + lo[j] * sn) * 0.125f);
        }
    }

    const ushort* kbase = Kr + (size_t)(b * NKVH + kvh) * SS * HD;
    const ushort* vbase = Vt + (size_t)(b * NKVH + kvh) * HD * SS;   // chunk-major

    f32x4 acc[2][4];
#pragma unroll
    for (int t = 0; t < 2; ++t)
#pragma unroll
        for (int i = 0; i < 4; ++i) acc[t][i] = (f32x4){0.f, 0.f, 0.f, 0.f};
    float psum[2] = {0.f, 0.f};

    // ds_bpermute byte indices for the P quad-exchange
    const int idxAB = (lo16 + ((quad & 1) << 5)) << 2;   // src quad {0,2,0,2}
    const int idxCD = idxAB + 64;                        // src quad {1,3,1,3}
    const bool hiq  = quad >= 2;

    int klo = q0 - WIN; if (klo < 0) klo = 0;
    const int khi = q0 + 31;
    const int n   = (khi - klo + 32) >> 5;   // total chunks (1..9)
    const int n0  = (n + 1) >> 1;            // chunks for wave 0
    const int cnt = wv ? (n - n0) : n0;      // may be 0 (qblk 0, wave 1)
    const int kb0 = klo + (wv ? n0 * 32 : 0);

    short8 kcur[4], vcur[4];
    {
        int key0 = kb0 + lo16, key1 = kb0 + 16 + lo16;   // always in-bounds
        kcur[0] = *(const short8*)(kbase + (size_t)key0 * HD + quad * 8);
        kcur[1] = *(const short8*)(kbase + (size_t)key0 * HD + 32 + quad * 8);
        kcur[2] = *(const short8*)(kbase + (size_t)key1 * HD + quad * 8);
        kcur[3] = *(const short8*)(kbase + (size_t)key1 * HD + 32 + quad * 8);
        int cidx = kb0 >> 5;
#pragma unroll
        for (int i = 0; i < 4; ++i)
            vcur[i] = *(const short8*)(vbase + (size_t)cidx * (HD * 32)
                                             + (i * 16 + lo16) * 32 + quad * 8);
    }

    for (int it = 0; it < cnt; ++it) {
        const int kb = kb0 + it * 32;
        const f32x4 z = {0.f, 0.f, 0.f, 0.f};
        // S^T = K·Q^T : C[row=key(quad*4+r)][col=query(lo16)]
        __builtin_amdgcn_s_setprio(1);
        f32x4 s00 = __builtin_amdgcn_mfma_f32_16x16x32_bf16(kcur[0], aq[0][0], z,   0, 0, 0);
        s00       = __builtin_amdgcn_mfma_f32_16x16x32_bf16(kcur[1], aq[0][1], s00, 0, 0, 0);
        f32x4 s01 = __builtin_amdgcn_mfma_f32_16x16x32_bf16(kcur[2], aq[0][0], z,   0, 0, 0);
        s01       = __builtin_amdgcn_mfma_f32_16x16x32_bf16(kcur[3], aq[0][1], s01, 0, 0, 0);
        f32x4 s10 = __builtin_amdgcn_mfma_f32_16x16x32_bf16(kcur[0], aq[1][0], z,   0, 0, 0);
        s10       = __builtin_amdgcn_mfma_f32_16x16x32_bf16(kcur[1], aq[1][1], s10, 0, 0, 0);
        f32x4 s11 = __builtin_amdgcn_mfma_f32_16x16x32_bf16(kcur[2], aq[1][0], z,   0, 0, 0);
        s11       = __builtin_amdgcn_mfma_f32_16x16x32_bf16(kcur[3], aq[1][1], s11, 0, 0, 0);
        __builtin_amdgcn_s_setprio(0);

        // prefetch next K AND V chunk (clamped; phantom chunk harmless)
        short8 knxt[4], vnxt[4];
        {
            int key0 = kb + 32 + lo16; if (key0 > SS - 1) key0 = SS - 1;
            int key1 = key0 + 16;      if (key1 > SS - 1) key1 = SS - 1;
            knxt[0] = *(const short8*)(kbase + (size_t)key0 * HD + quad * 8);
            knxt[1] = *(const short8*)(kbase + (size_t)key0 * HD + 32 + quad * 8);
            knxt[2] = *(const short8*)(kbase + (size_t)key1 * HD + quad * 8);
            knxt[3] = *(const short8*)(kbase + (size_t)key1 * HD + 32 + quad * 8);
            int cnx = (kb >> 5) + 1; if (cnx > (SS / 32) - 1) cnx = (SS / 32) - 1;
#pragma unroll
            for (int i = 0; i < 4; ++i)
                vnxt[i] = *(const short8*)(vbase + (size_t)cnx * (HD * 32)
                                                 + (i * 16 + lo16) * 32 + quad * 8);
        }

        // softmax numerator + in-register P transform to PV A-frag layout
        short8 ap[2];
#pragma unroll
        for (int t = 0; t < 2; ++t) {
            const f32x4 sa = t ? s10 : s00;
            const f32x4 sb = t ? s11 : s01;
            const int qtmin = q0 + t * 16;
            const int myq   = qtmin + lo16;
            float p[8];
            if ((kb + 31 > qtmin) || (kb < qtmin + 15 - WIN)) {   // boundary chunk: mask
#pragma unroll
                for (int r = 0; r < 4; ++r) {
                    int key0 = kb + quad * 4 + r;
                    int key1 = key0 + 16;
                    p[r]     = (key0 <= myq && key0 >= myq - WIN) ? __expf(sa[r]) : 0.f;
                    p[4 + r] = (key1 <= myq && key1 >= myq - WIN) ? __expf(sb[r]) : 0.f;
                }
            } else {                                              // interior: no mask
#pragma unroll
                for (int r = 0; r < 4; ++r) { p[r] = __expf(sa[r]); p[4 + r] = __expf(sb[r]); }
            }
            psum[t] += ((p[0] + p[1]) + (p[2] + p[3])) + ((p[4] + p[5]) + (p[6] + p[7]));

            // lane holds keys {4q..4q+3, 16+4q..16+4q+3} for query lo16;
            // A-frag needs keys {8q..8q+7} for query lo16 -> cross-quad pull.
            int w0 = cvtpk_bf16(p[0], p[1]);
            int w1 = cvtpk_bf16(p[2], p[3]);
            int w2 = cvtpk_bf16(p[4], p[5]);
            int w3 = cvtpk_bf16(p[6], p[7]);
            int a0 = __builtin_amdgcn_ds_bpermute(idxAB, w0);
            int a2 = __builtin_amdgcn_ds_bpermute(idxAB, w2);
            int b1 = __builtin_amdgcn_ds_bpermute(idxAB, w1);
            int b3 = __builtin_amdgcn_ds_bpermute(idxAB, w3);
            int c0 = __builtin_amdgcn_ds_bpermute(idxCD, w0);
            int c2 = __builtin_amdgcn_ds_bpermute(idxCD, w2);
            int d1 = __builtin_amdgcn_ds_bpermute(idxCD, w1);
            int d3 = __builtin_amdgcn_ds_bpermute(idxCD, w3);
            union { int i[4]; short8 s; } u;
            u.i[0] = hiq ? a2 : a0;   // keys 8q+0,1
            u.i[1] = hiq ? b3 : b1;   // keys 8q+2,3
            u.i[2] = hiq ? c2 : c0;   // keys 8q+4,5
            u.i[3] = hiq ? d3 : d1;   // keys 8q+6,7
            ap[t] = u.s;
        }

        __builtin_amdgcn_s_setprio(1);
#pragma unroll
        for (int i = 0; i < 4; ++i)
            acc[0][i] = __builtin_amdgcn_mfma_f32_16x16x32_bf16(ap[0], vcur[i], acc[0][i], 0, 0, 0);
#pragma unroll
        for (int i = 0; i < 4; ++i)
            acc[1][i] = __builtin_amdgcn_mfma_f32_16x16x32_bf16(ap[1], vcur[i], acc[1][i], 0, 0, 0);
        __builtin_amdgcn_s_setprio(0);

#pragma unroll
        for (int i = 0; i < 4; ++i) { kcur[i] = knxt[i]; vcur[i] = vnxt[i]; }
    }

    // ---- combine the two window-halves ----
    float pst[2];
#pragma unroll
    for (int t = 0; t < 2; ++t) {
        float ps = psum[t];
        ps += __shfl_xor(ps, 16, 64);
        ps += __shfl_xor(ps, 32, 64);        // all lanes: this half's total for query lo16
        pst[t] = ps;
    }
    if (wv == 1) {
#pragma unroll
        for (int t = 0; t < 2; ++t)
#pragma unroll
            for (int r = 0; r < 4; ++r) {
                int q = t * 16 + quad * 4 + r;
#pragma unroll
                for (int i = 0; i < 4; ++i)
                    cbuf[q][i * 16 + lo16] = acc[t][i][r];
            }
        if (quad == 0) { csum[lo16] = pst[0]; csum[16 + lo16] = pst[1]; }
    }
    __syncthreads();
    if (wv == 0) {
        pst[0] += csum[lo16];
        pst[1] += csum[16 + lo16];
#pragma unroll
        for (int t = 0; t < 2; ++t)
#pragma unroll
            for (int r = 0; r < 4; ++r) {
                int q = t * 16 + quad * 4 + r;
#pragma unroll
                for (int i = 0; i < 4; ++i)
                    acc[t][i][r] += cbuf[q][i * 16 + lo16];
            }
#pragma unroll
        for (int t = 0; t < 2; ++t) {
#pragma unroll
            for (int r = 0; r < 4; ++r) {
                float invr = 1.f / __shfl(pst[t], quad * 4 + r, 16);
                int qr = q0 + t * 16 + quad * 4 + r;
                size_t orow = ((size_t)(b * SS + qr) * NH + h) * HD;
                O[orow + 0 * 16 + lo16] = acc[t][0][r] * invr;
                O[orow + 1 * 16 + lo16] = acc[t][1][r] * invr;
                O[orow + 2 * 16 + lo16] = acc[t][2][r] * invr;
                O[orow + 3 * 16 + lo16] = acc[t][3][r] * invr;
            }
        }
    }
}

// ---------- fallback (no workspace): round-1 scalar kernel ----------
__device__ __forceinline__ float wave_sum(float x) {
#pragma unroll
    for (int off = 32; off > 0; off >>= 1) x += __shfl_xor(x, off, 64);
    return x;
}

__global__ __launch_bounds__(256) void attn_scalar(const float* __restrict__ Q,
                                                   const float* __restrict__ K,
                                                   const float* __restrict__ V,
                                                   float* __restrict__ O) {
    int wave = blockIdx.x * 4 + (threadIdx.x >> 6);
    int lane = threadIdx.x & 63;
    int q  = wave % SS;
    int bh = wave / SS;
    int h  = bh % NH;
    int b  = bh / NH;
    int kvh = h >> 2;

    float inv = __powf(10000.f, -(float)(lane & 31) * (1.f / 32.f));
    float sn, cs;
    __sincosf((float)q * inv, &sn, &cs);

    float qv = Q[(size_t)(b * SS + q) * (NH * HD) + h * HD + lane];
    float qpart = __shfl(qv, lane ^ 32, 64);
    float qrot = (qv * cs + ((lane < 32) ? -qpart : qpart) * sn) * 0.125f;

    const float* vbase = V + (size_t)b * SS * (NKVH * HD) + kvh * HD;
    float m = -1e30f, l = 0.f, acc = 0.f;
    int k0 = q - WIN; if (k0 < 0) k0 = 0;
    for (int k = k0; k <= q; ++k) {
        float kraw = K[(size_t)(b * SS + k) * (NKVH * HD) + kvh * HD + lane];
        float kpart = __shfl(kraw, lane ^ 32, 64);
        float ksn, kcs;
        __sincosf((float)k * inv, &ksn, &kcs);
        float kv = kraw * kcs + ((lane < 32) ? -kpart : kpart) * ksn;
        float vv = vbase[(size_t)k * (NKVH * HD) + lane];
        float score = wave_sum(qrot * kv);
        float mnew  = fmaxf(m, score);
        float alpha = __expf(m - mnew);
        float p     = __expf(score - mnew);
        l   = l * alpha + p;
        acc = acc * alpha + p * vv;
        m   = mnew;
    }
    O[(((size_t)(b * SS + q) * NH) + h) * HD + lane] = acc / l;
}

extern "C" void kernel_launch(void* const* d_in, const int* in_sizes, int n_in,
                              void* d_out, int out_size, void* d_ws, size_t ws_size,
                              hipStream_t stream) {
    const float* Q = (const float*)d_in[0];
    const float* K = (const float*)d_in[1];
    const float* V = (const float*)d_in[2];
    float* O = (float*)d_out;

    size_t kv_elems = (size_t)BB * NKVH * SS * HD;   // 2M elements
    size_t need = 2 * kv_elems * sizeof(ushort);     // 8 MB

    if (ws_size >= need) {
        ushort* Kr = (ushort*)d_ws;
        ushort* Vt = Kr + kv_elems;
        prep_kv<<<BB * NKVH * (SS / 32), 256, 0, stream>>>(K, V, Kr, Vt);
        attn_mfma<<<BB * NKVH * (SS / 32) * 4, 128, 0, stream>>>(Q, Kr, Vt, O);
    } else {
        attn_scalar<<<(BB * NH * SS) / 4, 256, 0, stream>>>(Q, K, V, O);
    }
}

// Round 4
// 114.822 us; speedup vs baseline: 1.1848x; 1.1848x over previous
//
#include <hip/hip_runtime.h>
#include <math.h>

#define NH   32
#define NKVH 8
#define HD   64
#define WIN  256
#define BB   2
#define SS   2048

typedef short short8 __attribute__((ext_vector_type(8)));
typedef float f32x4  __attribute__((ext_vector_type(4)));

__device__ __forceinline__ ushort f2bf(float x) {
    union { float f; unsigned u; } v; v.f = x;
    unsigned u = v.u + 0x7FFF + ((v.u >> 16) & 1);   // RNE
    return (ushort)(u >> 16);
}

__device__ __forceinline__ int cvtpk_bf16(float lo, float hi) {
    int r;
    asm("v_cvt_pk_bf16_f32 %0, %1, %2" : "=v"(r) : "v"(lo), "v"(hi));
    return r;
}

// XOR-swizzle within a 4KB chunk: spreads 128B-rows across 16B slots.
// Applied at prep-store AND lds-read (both-sides rule); global_load_lds
// stages the chunk linearly so LDS holds the same swizzled image.
__device__ __forceinline__ int swz(int L) { return L ^ (((L >> 7) & 7) << 4); }

__device__ __forceinline__ void stage16(const void* g, void* l) {
    __builtin_amdgcn_global_load_lds(
        (const __attribute__((address_space(1))) unsigned int*)g,
        (__attribute__((address_space(3))) unsigned int*)l, 16, 0, 0);
}

// ---- fused pre-pass: RoPE K -> bf16 chunks; V -> bf16 chunk-major transposed ----
// Kr chunk (4KB): rows = key%32 (128B = 64 d * 2B), XOR-swizzled.
// Vt chunk (4KB): rows = d (64B = 32 keys * 2B), XOR-swizzled.
__global__ __launch_bounds__(256) void prep_kv(const float* __restrict__ K,
                                               const float* __restrict__ V,
                                               ushort* __restrict__ Kr,
                                               ushort* __restrict__ Vt) {
    __shared__ ushort tile[32][65];
    const int bidx = blockIdx.x;                // (b, kvh, sblk): 2*8*64
    const int sblk = bidx & 63;
    const int s0   = sblk * 32;
    const int kvh  = (bidx >> 6) & 7;
    const int b    = bidx >> 9;
    const int d = threadIdx.x & 63, g = threadIdx.x >> 6;   // g 0..3, 8 rows each

    const float inv = __powf(10000.f, -(float)(d & 31) * (1.f / 32.f));

    float kv[8], vv[8];
#pragma unroll
    for (int i = 0; i < 8; ++i) {
        int s = s0 + g * 8 + i;
        kv[i] = K[(size_t)(b * SS + s) * (NKVH * HD) + kvh * HD + d];
        vv[i] = V[(size_t)(b * SS + s) * (NKVH * HD) + kvh * HD + d];
    }
    char* kc = (char*)(Kr + (size_t)(b * NKVH + kvh) * SS * HD) + (size_t)sblk * 4096;
#pragma unroll
    for (int i = 0; i < 8; ++i) {
        int s  = s0 + g * 8 + i;
        int sl = g * 8 + i;
        float partner = __shfl(kv[i], d ^ 32, 64);
        float sn, cs;
        __sincosf((float)s * inv, &sn, &cs);
        float krot = kv[i] * cs + ((d < 32) ? -partner : partner) * sn;
        *(ushort*)(kc + swz(sl * 128 + d * 2)) = f2bf(krot);
        tile[sl][d] = f2bf(vv[i]);
    }
    __syncthreads();
    char* vc = (char*)(Vt + (size_t)(b * NKVH + kvh) * HD * SS) + (size_t)sblk * 4096;
    const int sl2 = (threadIdx.x & 15) * 2, drg = threadIdx.x >> 4;   // drg 0..15
#pragma unroll
    for (int i = 0; i < 4; ++i) {
        int dr = drg * 4 + i;
        ushort2 u = make_ushort2(tile[sl2][dr], tile[sl2 + 1][dr]);
        *(ushort2*)(vc + swz(dr * 64 + sl2 * 2)) = u;
    }
}

// ---- main: block = 4 waves = 4 GQA heads of one kvh, SHARED K/V via LDS ----
// K+V chunk staged ONCE per block (global_load_lds x2 per wave), double-buffered,
// 2-phase schedule. In-register P exchange, setprio, XCD swizzle unchanged.
__global__ __launch_bounds__(256, 4) void attn_mfma(const float* __restrict__ Q,
                                                    const ushort* __restrict__ Kr,
                                                    const ushort* __restrict__ Vt,
                                                    float* __restrict__ O) {
    __shared__ __align__(16) ushort ldsK[2][2048];
    __shared__ __align__(16) ushort ldsV[2][2048];
    const int wv = threadIdx.x >> 6, lane = threadIdx.x & 63;
    const int lo16 = lane & 15, quad = lane >> 4;
    // bijective XCD swizzle: 1024 wg = 8 XCD * 128 contiguous
    const int bidx = (blockIdx.x & 7) * 128 + (blockIdx.x >> 3);
    const int qblk = bidx & 63;
    const int kvh  = (bidx >> 6) & 7;
    const int b    = bidx >> 9;
    const int h    = kvh * 4 + wv;
    const int q0   = qblk * 32;

    float invf[8];
#pragma unroll
    for (int j = 0; j < 8; ++j)
        invf[j] = __powf(10000.f, -(float)(quad * 8 + j) * (1.f / 32.f));

    // Q load + RoPE + scale -> MFMA B-operand-shaped regs
    short8 aq[2][2];
#pragma unroll
    for (int t = 0; t < 2; ++t) {
        int qi = q0 + t * 16 + lo16;
        const float* qrow = Q + (size_t)(b * SS + qi) * (NH * HD) + h * HD;
        float lo[8], hi[8];
        *(float4*)(lo)     = *(const float4*)(qrow + quad * 8);
        *(float4*)(lo + 4) = *(const float4*)(qrow + quad * 8 + 4);
        *(float4*)(hi)     = *(const float4*)(qrow + 32 + quad * 8);
        *(float4*)(hi + 4) = *(const float4*)(qrow + 32 + quad * 8 + 4);
#pragma unroll
        for (int j = 0; j < 8; ++j) {
            float sn, cs;
            __sincosf((float)qi * invf[j], &sn, &cs);
            aq[t][0][j] = (short)f2bf((lo[j] * cs - hi[j] * sn) * 0.125f);
            aq[t][1][j] = (short)f2bf((hi[j] * cs + lo[j] * sn) * 0.125f);
        }
    }

    const char* kbase = (const char*)(Kr + (size_t)(b * NKVH + kvh) * SS * HD);
    const char* vbase = (const char*)(Vt + (size_t)(b * NKVH + kvh) * HD * SS);

    f32x4 acc[2][4];
#pragma unroll
    for (int t = 0; t < 2; ++t)
#pragma unroll
        for (int i = 0; i < 4; ++i) acc[t][i] = (f32x4){0.f, 0.f, 0.f, 0.f};
    float psum[2] = {0.f, 0.f};

    // ds_bpermute byte indices for the P quad-exchange
    const int idxAB = (lo16 + ((quad & 1) << 5)) << 2;   // src quad {0,2,0,2}
    const int idxCD = idxAB + 64;                        // src quad {1,3,1,3}
    const bool hiq  = quad >= 2;

    int klo = q0 - WIN; if (klo < 0) klo = 0;
    const int c0  = klo >> 5;
    const int cnt = (q0 >> 5) - c0 + 1;      // chunks in window (1..9)

    // prologue: stage chunk c0 into buf 0 (each wave: 1KB of K + 1KB of V)
    {
        const char* kc = kbase + (size_t)c0 * 4096 + wv * 1024 + lane * 16;
        const char* vc = vbase + (size_t)c0 * 4096 + wv * 1024 + lane * 16;
        stage16(kc, (char*)&ldsK[0][0] + wv * 1024);
        stage16(vc, (char*)&ldsV[0][0] + wv * 1024);
    }
    __syncthreads();

    int nb = 0;
    for (int it = 0; it < cnt; ++it, nb ^= 1) {
        const int kb = klo + it * 32;
        // stage next chunk into the other buffer (overlaps with compute below;
        // the end-of-iter __syncthreads drains vmcnt before it's read)
        if (it + 1 < cnt) {
            const char* kc = kbase + (size_t)(c0 + it + 1) * 4096 + wv * 1024 + lane * 16;
            const char* vc = vbase + (size_t)(c0 + it + 1) * 4096 + wv * 1024 + lane * 16;
            stage16(kc, (char*)&ldsK[nb ^ 1][0] + wv * 1024);
            stage16(vc, (char*)&ldsV[nb ^ 1][0] + wv * 1024);
        }

        // K fragments from swizzled LDS (conflict-free-spread ds_read_b128)
        const char* kl = (const char*)&ldsK[nb][0];
        short8 k0 = *(const short8*)(kl + swz(lo16 * 128 + quad * 16));
        short8 k1 = *(const short8*)(kl + swz(lo16 * 128 + 64 + quad * 16));
        short8 k2 = *(const short8*)(kl + swz((lo16 + 16) * 128 + quad * 16));
        short8 k3 = *(const short8*)(kl + swz((lo16 + 16) * 128 + 64 + quad * 16));

        const f32x4 z = {0.f, 0.f, 0.f, 0.f};
        // S^T = K·Q^T : C[row=key(quad*4+r)][col=query(lo16)]
        __builtin_amdgcn_s_setprio(1);
        f32x4 s00 = __builtin_amdgcn_mfma_f32_16x16x32_bf16(k0, aq[0][0], z,   0, 0, 0);
        s00       = __builtin_amdgcn_mfma_f32_16x16x32_bf16(k1, aq[0][1], s00, 0, 0, 0);
        f32x4 s01 = __builtin_amdgcn_mfma_f32_16x16x32_bf16(k2, aq[0][0], z,   0, 0, 0);
        s01       = __builtin_amdgcn_mfma_f32_16x16x32_bf16(k3, aq[0][1], s01, 0, 0, 0);
        f32x4 s10 = __builtin_amdgcn_mfma_f32_16x16x32_bf16(k0, aq[1][0], z,   0, 0, 0);
        s10       = __builtin_amdgcn_mfma_f32_16x16x32_bf16(k1, aq[1][1], s10, 0, 0, 0);
        f32x4 s11 = __builtin_amdgcn_mfma_f32_16x16x32_bf16(k2, aq[1][0], z,   0, 0, 0);
        s11       = __builtin_amdgcn_mfma_f32_16x16x32_bf16(k3, aq[1][1], s11, 0, 0, 0);
        __builtin_amdgcn_s_setprio(0);

        // softmax numerator + in-register P transform to PV A-frag layout
        short8 ap[2];
#pragma unroll
        for (int t = 0; t < 2; ++t) {
            const f32x4 sa = t ? s10 : s00;
            const f32x4 sb = t ? s11 : s01;
            const int qtmin = q0 + t * 16;
            const int myq   = qtmin + lo16;
            float p[8];
            if ((kb + 31 > qtmin) || (kb < qtmin + 15 - WIN)) {   // boundary chunk: mask
#pragma unroll
                for (int r = 0; r < 4; ++r) {
                    int key0 = kb + quad * 4 + r;
                    int key1 = key0 + 16;
                    p[r]     = (key0 <= myq && key0 >= myq - WIN) ? __expf(sa[r]) : 0.f;
                    p[4 + r] = (key1 <= myq && key1 >= myq - WIN) ? __expf(sb[r]) : 0.f;
                }
            } else {                                              // interior: no mask
#pragma unroll
                for (int r = 0; r < 4; ++r) { p[r] = __expf(sa[r]); p[4 + r] = __expf(sb[r]); }
            }
            psum[t] += ((p[0] + p[1]) + (p[2] + p[3])) + ((p[4] + p[5]) + (p[6] + p[7]));

            // lane holds keys {4q..4q+3, 16+4q..16+4q+3} for query lo16;
            // A-frag needs keys {8q..8q+7} for query lo16 -> cross-quad pull.
            int w0 = cvtpk_bf16(p[0], p[1]);
            int w1 = cvtpk_bf16(p[2], p[3]);
            int w2 = cvtpk_bf16(p[4], p[5]);
            int w3 = cvtpk_bf16(p[6], p[7]);
            int a0 = __builtin_amdgcn_ds_bpermute(idxAB, w0);
            int a2 = __builtin_amdgcn_ds_bpermute(idxAB, w2);
            int b1 = __builtin_amdgcn_ds_bpermute(idxAB, w1);
            int b3 = __builtin_amdgcn_ds_bpermute(idxAB, w3);
            int cc0 = __builtin_amdgcn_ds_bpermute(idxCD, w0);
            int cc2 = __builtin_amdgcn_ds_bpermute(idxCD, w2);
            int d1 = __builtin_amdgcn_ds_bpermute(idxCD, w1);
            int d3 = __builtin_amdgcn_ds_bpermute(idxCD, w3);
            union { int i[4]; short8 s; } u;
            u.i[0] = hiq ? a2  : a0;    // keys 8q+0,1
            u.i[1] = hiq ? b3  : b1;    // keys 8q+2,3
            u.i[2] = hiq ? cc2 : cc0;   // keys 8q+4,5
            u.i[3] = hiq ? d3  : d1;    // keys 8q+6,7
            ap[t] = u.s;
        }

        // V fragments from swizzled LDS
        const char* vl = (const char*)&ldsV[nb][0];
        short8 vf[4];
#pragma unroll
        for (int i = 0; i < 4; ++i)
            vf[i] = *(const short8*)(vl + swz((i * 16 + lo16) * 64 + quad * 16));

        __builtin_amdgcn_s_setprio(1);
#pragma unroll
        for (int i = 0; i < 4; ++i)
            acc[0][i] = __builtin_amdgcn_mfma_f32_16x16x32_bf16(ap[0], vf[i], acc[0][i], 0, 0, 0);
#pragma unroll
        for (int i = 0; i < 4; ++i)
            acc[1][i] = __builtin_amdgcn_mfma_f32_16x16x32_bf16(ap[1], vf[i], acc[1][i], 0, 0, 0);
        __builtin_amdgcn_s_setprio(0);

        __syncthreads();   // drains vmcnt (stage done) + guards buffer reuse
    }

#pragma unroll
    for (int t = 0; t < 2; ++t) {
        float ps = psum[t];
        ps += __shfl_xor(ps, 16, 64);
        ps += __shfl_xor(ps, 32, 64);        // all lanes: total for query lo16
#pragma unroll
        for (int r = 0; r < 4; ++r) {
            float invr = 1.f / __shfl(ps, quad * 4 + r, 16);
            int qr = q0 + t * 16 + quad * 4 + r;
            size_t orow = ((size_t)(b * SS + qr) * NH + h) * HD;
            O[orow + 0 * 16 + lo16] = acc[t][0][r] * invr;
            O[orow + 1 * 16 + lo16] = acc[t][1][r] * invr;
            O[orow + 2 * 16 + lo16] = acc[t][2][r] * invr;
            O[orow + 3 * 16 + lo16] = acc[t][3][r] * invr;
        }
    }
}

// ---------- fallback (no workspace): round-1 scalar kernel ----------
__device__ __forceinline__ float wave_sum(float x) {
#pragma unroll
    for (int off = 32; off > 0; off >>= 1) x += __shfl_xor(x, off, 64);
    return x;
}

__global__ __launch_bounds__(256) void attn_scalar(const float* __restrict__ Q,
                                                   const float* __restrict__ K,
                                                   const float* __restrict__ V,
                                                   float* __restrict__ O) {
    int wave = blockIdx.x * 4 + (threadIdx.x >> 6);
    int lane = threadIdx.x & 63;
    int q  = wave % SS;
    int bh = wave / SS;
    int h  = bh % NH;
    int b  = bh / NH;
    int kvh = h >> 2;

    float inv = __powf(10000.f, -(float)(lane & 31) * (1.f / 32.f));
    float sn, cs;
    __sincosf((float)q * inv, &sn, &cs);

    float qv = Q[(size_t)(b * SS + q) * (NH * HD) + h * HD + lane];
    float qpart = __shfl(qv, lane ^ 32, 64);
    float qrot = (qv * cs + ((lane < 32) ? -qpart : qpart) * sn) * 0.125f;

    const float* vbase = V + (size_t)b * SS * (NKVH * HD) + kvh * HD;
    float m = -1e30f, l = 0.f, acc = 0.f;
    int k0 = q - WIN; if (k0 < 0) k0 = 0;
    for (int k = k0; k <= q; ++k) {
        float kraw = K[(size_t)(b * SS + k) * (NKVH * HD) + kvh * HD + lane];
        float kpart = __shfl(kraw, lane ^ 32, 64);
        float ksn, kcs;
        __sincosf((float)k * inv, &ksn, &kcs);
        float kv = kraw * kcs + ((lane < 32) ? -kpart : kpart) * ksn;
        float vv = vbase[(size_t)k * (NKVH * HD) + lane];
        float score = wave_sum(qrot * kv);
        float mnew  = fmaxf(m, score);
        float alpha = __expf(m - mnew);
        float p     = __expf(score - mnew);
        l   = l * alpha + p;
        acc = acc * alpha + p * vv;
        m   = mnew;
    }
    O[(((size_t)(b * SS + q) * NH) + h) * HD + lane] = acc / l;
}

extern "C" void kernel_launch(void* const* d_in, const int* in_sizes, int n_in,
                              void* d_out, int out_size, void* d_ws, size_t ws_size,
                              hipStream_t stream) {
    const float* Q = (const float*)d_in[0];
    const float* K = (const float*)d_in[1];
    const float* V = (const float*)d_in[2];
    float* O = (float*)d_out;

    size_t kv_elems = (size_t)BB * NKVH * SS * HD;   // 2M elements
    size_t need = 2 * kv_elems * sizeof(ushort);     // 8 MB

    if (ws_size >= need) {
        ushort* Kr = (ushort*)d_ws;
        ushort* Vt = Kr + kv_elems;
        prep_kv<<<BB * NKVH * (SS / 32), 256, 0, stream>>>(K, V, Kr, Vt);
        attn_mfma<<<BB * NKVH * (SS / 32), 256, 0, stream>>>(Q, Kr, Vt, O);
    } else {
        attn_scalar<<<(BB * NH * SS) / 4, 256, 0, stream>>>(Q, K, V, O);
    }
}